// Round 6
// baseline (241.913 us; speedup 1.0000x reference)
//
#include <hip/hip_runtime.h>
#include <math.h>

#define NN   10000     // nodes
#define NBAT 4         // batch
#define NE   160000    // edges
#define EPSV 1e-8f

typedef _Float16 f16;
typedef _Float16 f16x8 __attribute__((ext_vector_type(8)));
typedef float    f32x4 __attribute__((ext_vector_type(4)));

// ---------------------------------------------------------------------------
// degree + count accumulation (merged)
__global__ void k_degcnt(const float* __restrict__ ew, const int* __restrict__ row,
                         const int* __restrict__ col, float* __restrict__ dout,
                         float* __restrict__ din, int* __restrict__ cnt_out,
                         int* __restrict__ cnt_in) {
    int e = blockIdx.x * 256 + threadIdx.x;
    if (e < NE) {
        float w = ew[e];
        int r = row[e], c = col[e];
        atomicAdd(&dout[r], w);
        atomicAdd(&din[c], w);
        atomicAdd(&cnt_out[c], 1);   // A_out scatters to col
        atomicAdd(&cnt_in[r], 1);    // A_in  scatters to row
    }
}

// exclusive scan over N=10000 counts; blockIdx.x selects which CSR
__global__ void k_scan(const int* __restrict__ cnt_out, int* __restrict__ ptr_out, int* __restrict__ cur_out,
                       const int* __restrict__ cnt_in,  int* __restrict__ ptr_in,  int* __restrict__ cur_in) {
    const int* cnt = blockIdx.x ? cnt_in : cnt_out;
    int* ptr = blockIdx.x ? ptr_in : ptr_out;
    int* cur = blockIdx.x ? cur_in : cur_out;
    __shared__ int part[1024];
    int t = threadIdx.x;
    int c0 = t * 10, c1 = min(c0 + 10, NN);
    int s = 0;
    for (int i = c0; i < c1; i++) s += cnt[i];
    part[t] = s;
    __syncthreads();
    for (int off = 1; off < 1024; off <<= 1) {
        int v = (t >= off) ? part[t - off] : 0;
        __syncthreads();
        part[t] += v;
        __syncthreads();
    }
    int run = t ? part[t - 1] : 0;
    for (int i = c0; i < c1; i++) { ptr[i] = run; cur[i] = run; run += cnt[i]; }
    if (t == 1023) ptr[NN] = part[1023];
}

// fill CSR entries; weight = 1/(deg+eps) computed inline
__global__ void k_fill(const int* __restrict__ row, const int* __restrict__ col,
                       const float* __restrict__ deg_out, const float* __restrict__ deg_in,
                       int* __restrict__ cur_out, int* __restrict__ srcs_out, float* __restrict__ w_out,
                       int* __restrict__ cur_in,  int* __restrict__ srcs_in,  float* __restrict__ w_in) {
    int e = blockIdx.x * 256 + threadIdx.x;
    if (e >= NE) return;
    int r = row[e], c = col[e];
    int po = atomicAdd(&cur_out[c], 1);
    srcs_out[po] = r;  w_out[po] = 1.f / (deg_out[r] + EPSV);
    int pi = atomicAdd(&cur_in[r], 1);
    srcs_in[pi] = c;   w_in[pi] = 1.f / (deg_in[c] + EPSV);
}

// ---------------------------------------------------------------------------
// build f16 concat rows: Xh16[node][0:64]=X, [64:128]=H   (node = b*NN+v)
__global__ void k_xh16(const float* __restrict__ X, const float* __restrict__ H,
                       f16* __restrict__ Xh) {
    int t = blockIdx.x * 256 + threadIdx.x;          // nBN*16 threads, 8 elems each
    int slot = t & 15;
    size_t node = (size_t)(t >> 4);
    int c0 = slot * 8;
    const float* src = (c0 < 64) ? (X + node * 64 + c0) : (H + node * 64 + (c0 - 64));
    float4 a = *(const float4*)src;
    float4 b = *(const float4*)(src + 4);
    f16x8 o;
    o[0] = (f16)a.x; o[1] = (f16)a.y; o[2] = (f16)a.z; o[3] = (f16)a.w;
    o[4] = (f16)b.x; o[5] = (f16)b.y; o[6] = (f16)b.z; o[7] = (f16)b.w;
    *(f16x8*)(Xh + node * 128 + c0) = o;
}

// ---------------------------------------------------------------------------
// f16 propagation, merged CSR pair, XCD-chunked block swizzle.
// y[b,v,:] = sum_j w[j] * x[b,src[j],:]
// HALFB = padded blocks per half (multiple of 8). Swizzle gives each XCD a
// contiguous node range -> banded source windows stay resident in its L2.
template <int D, int HALFB>
__global__ __launch_bounds__(256) void k_prop16(
        const int* __restrict__ pA, const int* __restrict__ sA, const float* __restrict__ wA,
        const f16* __restrict__ xA, f16* __restrict__ yA,
        const int* __restrict__ pB, const int* __restrict__ sB, const float* __restrict__ wB,
        const f16* __restrict__ xB, f16* __restrict__ yB) {
    constexpr int VEC = D / 8;   // f16x8 lanes per node
    bool second = blockIdx.x >= HALFB;
    int local = second ? blockIdx.x - HALFB : blockIdx.x;
    int swz = (local & 7) * (HALFB / 8) + (local >> 3);   // bijective on [0,HALFB)
    int tid = swz * 256 + threadIdx.x;
    if (tid >= NBAT * NN * VEC) return;
    const int* ptr   = second ? pB : pA;
    const int* srcs  = second ? sB : sA;
    const float* wts = second ? wB : wA;
    const f16* x     = second ? xB : xA;
    f16* y           = second ? yB : yA;
    int c8 = tid & (VEC - 1);
    int v  = (tid / VEC) % NN;
    int b  = tid / (VEC * NN);
    const f16* src = x + (size_t)b * NN * D + c8 * 8;
    int j0 = ptr[v], j1 = ptr[v + 1];
    float acc[8] = {};
    int j = j0;
    for (; j + 8 <= j1; j += 8) {
        int s[8]; float wv[8];
#pragma unroll
        for (int q = 0; q < 8; q++) { s[q] = srcs[j + q]; wv[q] = wts[j + q]; }
        f16x8 g[8];
#pragma unroll
        for (int q = 0; q < 8; q++) g[q] = *(const f16x8*)(src + (size_t)s[q] * D);
#pragma unroll
        for (int q = 0; q < 8; q++)
#pragma unroll
            for (int e = 0; e < 8; e++) acc[e] += wv[q] * (float)g[q][e];
    }
    for (; j < j1; j++) {
        float w = wts[j];
        f16x8 g = *(const f16x8*)(src + (size_t)srcs[j] * D);
#pragma unroll
        for (int e = 0; e < 8; e++) acc[e] += w * (float)g[e];
    }
    f16x8 o;
#pragma unroll
    for (int e = 0; e < 8; e++) o[e] = (f16)acc[e];
    ((f16x8*)y)[tid] = o;
}

// ---------------------------------------------------------------------------
// effective weights, TRANSPOSED + f16: Wt[g][o][kk], kk in [0,640)
//  blk0 (kk<128): W00+W10-W02-W12 ; blk1: W01 ; blk2: W11 ; blk3: 2*W02 ; blk4: 2*W12
__global__ void k_wprep16(const float* __restrict__ Wz, const float* __restrict__ Wr,
                          const float* __restrict__ Wh, f16* __restrict__ Wt) {
    int t = blockIdx.x * 256 + threadIdx.x;   // ((g*64+o)*640+kk)
    if (t >= 3 * 64 * 640) return;
    int kk = t % 640;
    int o  = (t / 640) & 63;
    int g  = t / (640 * 64);
    const float* W = (g == 0) ? Wz : (g == 1 ? Wr : Wh);
    int blk = kk >> 7, kin = kk & 127;
#define WIDX(d, k) W[(((d) * 3 + (k)) * 128 + kin) * 64 + o]
    float val;
    if (blk == 0)      val = WIDX(0, 0) + WIDX(1, 0) - WIDX(0, 2) - WIDX(1, 2);
    else if (blk == 1) val = WIDX(0, 1);
    else if (blk == 2) val = WIDX(1, 1);
    else if (blk == 3) val = 2.f * WIDX(0, 2);
    else               val = 2.f * WIDX(1, 2);
#undef WIDX
    Wt[t] = (f16)val;
}

// ---------------------------------------------------------------------------
// MFMA gate matmuls: [40000,640]@[640,64], A assembled from 10 f16 chunk sources
struct SrcTab16 {
    const f16* p[10];
    int ld[10];
    int co[10];
};

__device__ __forceinline__ float sigmf(float x) { return 1.f / (1.f + __expf(-x)); }
__device__ __forceinline__ float tanhfast(float x) {
    float e = __expf(2.f * x);
    return 1.f - 2.f / (e + 1.f);
}

// 64 rows x 64 cols per block, 4 waves; double-buffered LDS, 1 barrier/chunk.
__global__ __launch_bounds__(256) void k_gate_zr16(SrcTab16 tab,
        const f16* __restrict__ wtz, const f16* __restrict__ wtr,
        const float* __restrict__ bz, const float* __restrict__ br,
        const float* __restrict__ H, float* __restrict__ Z, f16* __restrict__ HR) {
    __shared__ f16 As[2][64 * 64];
    __shared__ f16 Ws[2][2][64 * 64];
    int tid = threadIdx.x;
    int l = tid & 63, w = tid >> 6;
    int g = l >> 4, li = l & 15;
    int rloc = w * 16 + li;
    int rb0 = blockIdx.x * 64;
    f32x4 accZ[4] = {}, accR[4] = {};
    f16x8 rA[2], rW[4];

    auto loadc = [&](int ch) {
        const f16* sp = tab.p[ch];
        int ld = tab.ld[ch], co = tab.co[ch];
#pragma unroll
        for (int i = 0; i < 2; i++) {
            int idx = i * 256 + tid;          // [0,512)
            int row = idx >> 3, slot = idx & 7;
            rA[i] = *(const f16x8*)(sp + (size_t)(rb0 + row) * ld + co + slot * 8);
        }
#pragma unroll
        for (int i = 0; i < 4; i++) {
            int idx = i * 256 + tid;          // [0,1024)
            int wsel = idx >> 9, id2 = idx & 511;
            int row = id2 >> 3, slot = id2 & 7;
            rW[i] = *(const f16x8*)((wsel ? wtr : wtz) + (size_t)row * 640 + ch * 64 + slot * 8);
        }
    };
    auto storec = [&](int buf) {
#pragma unroll
        for (int i = 0; i < 2; i++) {
            int idx = i * 256 + tid;
            int row = idx >> 3, slot = idx & 7;
            int byte = row * 128 + ((slot * 16) ^ ((row & 7) << 4));
            *(f16x8*)((char*)As[buf] + byte) = rA[i];
        }
#pragma unroll
        for (int i = 0; i < 4; i++) {
            int idx = i * 256 + tid;
            int wsel = idx >> 9, id2 = idx & 511;
            int row = id2 >> 3, slot = id2 & 7;
            int byte = row * 128 + ((slot * 16) ^ ((row & 7) << 4));
            *(f16x8*)((char*)Ws[buf][wsel] + byte) = rW[i];
        }
    };

    loadc(0); storec(0); __syncthreads();
    int cur = 0;
    for (int ch = 0; ch < 10; ch++) {
        if (ch + 1 < 10) loadc(ch + 1);
#pragma unroll
        for (int kk2 = 0; kk2 < 2; kk2++) {
            int k = kk2 * 32 + g * 8;
            f16x8 af = *(const f16x8*)((char*)As[cur] + rloc * 128 + ((k * 2) ^ ((rloc & 7) << 4)));
#pragma unroll
            for (int ct = 0; ct < 4; ct++) {
                int c = ct * 16 + li;
                int wbyte = c * 128 + ((k * 2) ^ ((c & 7) << 4));
                f16x8 bzf = *(const f16x8*)((char*)Ws[cur][0] + wbyte);
                f16x8 brf = *(const f16x8*)((char*)Ws[cur][1] + wbyte);
                accZ[ct] = __builtin_amdgcn_mfma_f32_16x16x32_f16(af, bzf, accZ[ct], 0, 0, 0);
                accR[ct] = __builtin_amdgcn_mfma_f32_16x16x32_f16(af, brf, accR[ct], 0, 0, 0);
            }
        }
        if (ch + 1 < 10) {
            storec(cur ^ 1);      // other buffer: no wave reads it this iter
            __syncthreads();
            cur ^= 1;
        }
    }
    // epilogue: C row = (lane>>4)*4 + reg, col = ct*16 + (lane&15)
#pragma unroll
    for (int ct = 0; ct < 4; ct++) {
        int c = ct * 16 + li;
        float zb = bz[c], rbv = br[c];
#pragma unroll
        for (int q = 0; q < 4; q++) {
            size_t row = (size_t)rb0 + w * 16 + g * 4 + q;
            float z = sigmf(accZ[ct][q] + zb);
            float r = sigmf(accR[ct][q] + rbv);
            Z[row * 64 + c] = z;
            HR[row * 64 + c] = (f16)(H[row * 64 + c] * r);
        }
    }
}

__global__ __launch_bounds__(256) void k_gate_h16(SrcTab16 tab,
        const f16* __restrict__ wth, const float* __restrict__ bh,
        const float* __restrict__ H, const float* __restrict__ Z,
        float* __restrict__ out) {
    __shared__ f16 As[2][64 * 64];
    __shared__ f16 Ws[2][64 * 64];
    int tid = threadIdx.x;
    int l = tid & 63, w = tid >> 6;
    int g = l >> 4, li = l & 15;
    int rloc = w * 16 + li;
    int rb0 = blockIdx.x * 64;
    f32x4 acc[4] = {};
    f16x8 rA[2], rW[2];

    auto loadc = [&](int ch) {
        const f16* sp = tab.p[ch];
        int ld = tab.ld[ch], co = tab.co[ch];
#pragma unroll
        for (int i = 0; i < 2; i++) {
            int idx = i * 256 + tid;
            int row = idx >> 3, slot = idx & 7;
            rA[i] = *(const f16x8*)(sp + (size_t)(rb0 + row) * ld + co + slot * 8);
            rW[i] = *(const f16x8*)(wth + (size_t)row * 640 + ch * 64 + slot * 8);
        }
    };
    auto storec = [&](int buf) {
#pragma unroll
        for (int i = 0; i < 2; i++) {
            int idx = i * 256 + tid;
            int row = idx >> 3, slot = idx & 7;
            int byte = row * 128 + ((slot * 16) ^ ((row & 7) << 4));
            *(f16x8*)((char*)As[buf] + byte) = rA[i];
            *(f16x8*)((char*)Ws[buf] + byte) = rW[i];
        }
    };

    loadc(0); storec(0); __syncthreads();
    int cur = 0;
    for (int ch = 0; ch < 10; ch++) {
        if (ch + 1 < 10) loadc(ch + 1);
#pragma unroll
        for (int kk2 = 0; kk2 < 2; kk2++) {
            int k = kk2 * 32 + g * 8;
            f16x8 af = *(const f16x8*)((char*)As[cur] + rloc * 128 + ((k * 2) ^ ((rloc & 7) << 4)));
#pragma unroll
            for (int ct = 0; ct < 4; ct++) {
                int c = ct * 16 + li;
                int wbyte = c * 128 + ((k * 2) ^ ((c & 7) << 4));
                f16x8 bf = *(const f16x8*)((char*)Ws[cur] + wbyte);
                acc[ct] = __builtin_amdgcn_mfma_f32_16x16x32_f16(af, bf, acc[ct], 0, 0, 0);
            }
        }
        if (ch + 1 < 10) {
            storec(cur ^ 1);
            __syncthreads();
            cur ^= 1;
        }
    }
#pragma unroll
    for (int ct = 0; ct < 4; ct++) {
        int c = ct * 16 + li;
        float hb = bh[c];
#pragma unroll
        for (int q = 0; q < 4; q++) {
            size_t row = (size_t)rb0 + w * 16 + g * 4 + q;
            float ht = tanhfast(acc[ct][q] + hb);
            float z = Z[row * 64 + c];
            out[row * 64 + c] = z * H[row * 64 + c] + (1.f - z) * ht;
        }
    }
}

// ---------------------------------------------------------------------------
extern "C" void kernel_launch(void* const* d_in, const int* in_sizes, int n_in,
                              void* d_out, int out_size, void* d_ws, size_t ws_size,
                              hipStream_t stream) {
    const float* X  = (const float*)d_in[0];
    const float* H  = (const float*)d_in[1];
    const float* ew = (const float*)d_in[2];
    const float* Wz = (const float*)d_in[3];
    const float* bz = (const float*)d_in[4];
    const float* Wr = (const float*)d_in[5];
    const float* br = (const float*)d_in[6];
    const float* Wh = (const float*)d_in[7];
    const float* bh = (const float*)d_in[8];
    const int*   ei = (const int*)d_in[9];
    const int* row = ei;
    const int* col = ei + NE;
    float* out = (float*)d_out;

    char* ws = (char*)d_ws;
    size_t off = 0;
    auto alloc = [&](size_t bytes) -> void* {
        void* p = ws + off;
        off += (bytes + 255) & ~(size_t)255;
        return p;
    };
    float* degs     = (float*)alloc(2 * NN * 4);
    int*   cnts     = (int*)alloc(2 * NN * 4);
    size_t zero_span = off;                      // degs..cnts: one memset covers both
    int*   ptr_out  = (int*)alloc((NN + 1) * 4);
    int*   cur_out  = (int*)alloc(NN * 4);
    int*   srcs_out = (int*)alloc(NE * 4);
    float* w_out    = (float*)alloc(NE * 4);
    int*   ptr_in   = (int*)alloc((NN + 1) * 4);
    int*   cur_in   = (int*)alloc(NN * 4);
    int*   srcs_in  = (int*)alloc(NE * 4);
    float* w_in     = (float*)alloc(NE * 4);
    const size_t nBN = (size_t)NBAT * NN;
    f16* Xh16 = (f16*)alloc(nBN * 128 * 2);
    f16* P1o  = (f16*)alloc(nBN * 128 * 2);
    f16* P1i  = (f16*)alloc(nBN * 128 * 2);
    f16* S1o  = (f16*)alloc(nBN * 128 * 2);
    f16* S1i  = (f16*)alloc(nBN * 128 * 2);
    f16* HRb  = (f16*)alloc(nBN * 64 * 2);
    f16* T1o  = (f16*)alloc(nBN * 64 * 2);
    f16* T1i  = (f16*)alloc(nBN * 64 * 2);
    f16* T2o  = (f16*)alloc(nBN * 64 * 2);
    f16* T2i  = (f16*)alloc(nBN * 64 * 2);
    float* Zb = (float*)alloc(nBN * 64 * 4);
    f16* Wt   = (f16*)alloc(3 * 64 * 640 * 2);
    f16* wtz = Wt;
    f16* wtr = Wt + 64 * 640;
    f16* wth = Wt + 2 * 64 * 640;

    float* deg_out = degs;
    float* deg_in  = degs + NN;
    int* cnt_out = cnts;
    int* cnt_in  = cnts + NN;

    hipMemsetAsync(degs, 0, zero_span, stream);

    int gE = (NE + 255) / 256;
    k_degcnt<<<gE, 256, 0, stream>>>(ew, row, col, deg_out, deg_in, cnt_out, cnt_in);
    k_scan<<<2, 1024, 0, stream>>>(cnt_out, ptr_out, cur_out, cnt_in, ptr_in, cur_in);
    k_fill<<<gE, 256, 0, stream>>>(row, col, deg_out, deg_in,
                                   cur_out, srcs_out, w_out, cur_in, srcs_in, w_in);

    // f16 concat build + weight prep
    k_xh16<<<(int)(nBN * 16 / 256), 256, 0, stream>>>(X, H, Xh16);
    k_wprep16<<<(3 * 64 * 640 + 255) / 256, 256, 0, stream>>>(Wz, Wr, Wh, Wt);

    // padded half-grids (multiple of 8 for XCD-chunked swizzle)
    constexpr int HB128 = ((NBAT * NN * 16 + 255) / 256 + 7) & ~7;   // 2504
    constexpr int HB64  = ((NBAT * NN * 8  + 255) / 256 + 7) & ~7;   // 1256

    // P1o = A_out [X|H], P1i = A_in [X|H]
    k_prop16<128, HB128><<<2 * HB128, 256, 0, stream>>>(
        ptr_out, srcs_out, w_out, Xh16, P1o, ptr_in, srcs_in, w_in, Xh16, P1i);
    // S1o = A_out P1o, S1i = A_in P1i
    k_prop16<128, HB128><<<2 * HB128, 256, 0, stream>>>(
        ptr_out, srcs_out, w_out, P1o, S1o, ptr_in, srcs_in, w_in, P1i, S1i);

    SrcTab16 zr;
    {
        const f16* ps[10] = {Xh16, Xh16, P1o, P1o, P1i, P1i, S1o, S1o, S1i, S1i};
        int lds[10] = {128, 128, 128, 128, 128, 128, 128, 128, 128, 128};
        int cos_[10] = {0, 64, 0, 64, 0, 64, 0, 64, 0, 64};
        for (int i = 0; i < 10; i++) { zr.p[i] = ps[i]; zr.ld[i] = lds[i]; zr.co[i] = cos_[i]; }
    }
    int gMM = (int)(nBN / 64);
    k_gate_zr16<<<gMM, 256, 0, stream>>>(zr, wtz, wtr, bz, br, H, Zb, HRb);

    // props of HR (64-dim)
    k_prop16<64, HB64><<<2 * HB64, 256, 0, stream>>>(
        ptr_out, srcs_out, w_out, HRb, T1o, ptr_in, srcs_in, w_in, HRb, T1i);
    k_prop16<64, HB64><<<2 * HB64, 256, 0, stream>>>(
        ptr_out, srcs_out, w_out, T1o, T2o, ptr_in, srcs_in, w_in, T1i, T2i);

    SrcTab16 hh;
    {
        const f16* ps[10] = {Xh16, HRb, P1o, T1o, P1i, T1i, S1o, T2o, S1i, T2i};
        int lds[10] = {128, 64, 128, 64, 128, 64, 128, 64, 128, 64};
        int cos_[10] = {0, 0, 0, 0, 0, 0, 0, 0, 0, 0};
        for (int i = 0; i < 10; i++) { hh.p[i] = ps[i]; hh.ld[i] = lds[i]; hh.co[i] = cos_[i]; }
    }
    k_gate_h16<<<gMM, 256, 0, stream>>>(hh, wth, bh, H, Zb, out);
}

// Round 8
// 231.165 us; speedup vs baseline: 1.0465x; 1.0465x over previous
//
#include <hip/hip_runtime.h>
#include <math.h>

#define NN   10000     // nodes
#define NBAT 4         // batch
#define NE   160000    // edges
#define EPSV 1e-8f

typedef _Float16 f16;
typedef _Float16 f16x8 __attribute__((ext_vector_type(8)));
typedef float    f32x4 __attribute__((ext_vector_type(4)));

// ---------------------------------------------------------------------------
// degree + count accumulation (merged)
__global__ void k_degcnt(const float* __restrict__ ew, const int* __restrict__ row,
                         const int* __restrict__ col, float* __restrict__ dout,
                         float* __restrict__ din, int* __restrict__ cnt_out,
                         int* __restrict__ cnt_in) {
    int e = blockIdx.x * 256 + threadIdx.x;
    if (e < NE) {
        float w = ew[e];
        int r = row[e], c = col[e];
        atomicAdd(&dout[r], w);
        atomicAdd(&din[c], w);
        atomicAdd(&cnt_out[c], 1);   // A_out scatters to col
        atomicAdd(&cnt_in[r], 1);    // A_in  scatters to row
    }
}

// exclusive scan over N=10000 counts; blockIdx.x selects which CSR
__global__ void k_scan(const int* __restrict__ cnt_out, int* __restrict__ ptr_out, int* __restrict__ cur_out,
                       const int* __restrict__ cnt_in,  int* __restrict__ ptr_in,  int* __restrict__ cur_in) {
    const int* cnt = blockIdx.x ? cnt_in : cnt_out;
    int* ptr = blockIdx.x ? ptr_in : ptr_out;
    int* cur = blockIdx.x ? cur_in : cur_out;
    __shared__ int part[1024];
    int t = threadIdx.x;
    int c0 = t * 10, c1 = min(c0 + 10, NN);
    int s = 0;
    for (int i = c0; i < c1; i++) s += cnt[i];
    part[t] = s;
    __syncthreads();
    for (int off = 1; off < 1024; off <<= 1) {
        int v = (t >= off) ? part[t - off] : 0;
        __syncthreads();
        part[t] += v;
        __syncthreads();
    }
    int run = t ? part[t - 1] : 0;
    for (int i = c0; i < c1; i++) { ptr[i] = run; cur[i] = run; run += cnt[i]; }
    if (t == 1023) ptr[NN] = part[1023];
}

// fill CSR entries; weight = 1/(deg+eps) computed inline
__global__ void k_fill(const int* __restrict__ row, const int* __restrict__ col,
                       const float* __restrict__ deg_out, const float* __restrict__ deg_in,
                       int* __restrict__ cur_out, int* __restrict__ srcs_out, float* __restrict__ w_out,
                       int* __restrict__ cur_in,  int* __restrict__ srcs_in,  float* __restrict__ w_in) {
    int e = blockIdx.x * 256 + threadIdx.x;
    if (e >= NE) return;
    int r = row[e], c = col[e];
    int po = atomicAdd(&cur_out[c], 1);
    srcs_out[po] = r;  w_out[po] = 1.f / (deg_out[r] + EPSV);
    int pi = atomicAdd(&cur_in[r], 1);
    srcs_in[pi] = c;   w_in[pi] = 1.f / (deg_in[c] + EPSV);
}

// ---------------------------------------------------------------------------
// merged prep: blocks [0,XHB) build node-major f16 concat rows
//   Xh[rr=v*4+b][0:64]=X[b][v], [64:128]=H[b][v]
// blocks [XHB, XHB+WPB) build transposed f16 effective weights Wt[g][o][kk]
//   blk0: W00+W10-W02-W12 ; blk1: W01 ; blk2: W11 ; blk3: 2*W02 ; blk4: 2*W12
#define XHB ((NBAT * NN * 16) / 256)          // 2500
#define WPB ((3 * 64 * 640 + 255) / 256)      // 480
__global__ void k_prep(const float* __restrict__ X, const float* __restrict__ H,
                       f16* __restrict__ Xh,
                       const float* __restrict__ Wz, const float* __restrict__ Wr,
                       const float* __restrict__ Wh, f16* __restrict__ Wt) {
    if (blockIdx.x < XHB) {
        int t = blockIdx.x * 256 + threadIdx.x;
        int slot = t & 15;
        int rr = t >> 4;
        int v = rr >> 2, b = rr & 3;
        int c0 = slot * 8;
        const float* src = (c0 < 64) ? (X + ((size_t)b * NN + v) * 64 + c0)
                                     : (H + ((size_t)b * NN + v) * 64 + (c0 - 64));
        float4 a = *(const float4*)src;
        float4 bb = *(const float4*)(src + 4);
        f16x8 o;
        o[0] = (f16)a.x; o[1] = (f16)a.y; o[2] = (f16)a.z; o[3] = (f16)a.w;
        o[4] = (f16)bb.x; o[5] = (f16)bb.y; o[6] = (f16)bb.z; o[7] = (f16)bb.w;
        *(f16x8*)(Xh + (size_t)rr * 128 + c0) = o;
    } else {
        int t = (blockIdx.x - XHB) * 256 + threadIdx.x;   // ((g*64+o)*640+kk)
        if (t >= 3 * 64 * 640) return;
        int kk = t % 640;
        int o  = (t / 640) & 63;
        int g  = t / (640 * 64);
        const float* W = (g == 0) ? Wz : (g == 1 ? Wr : Wh);
        int blk = kk >> 7, kin = kk & 127;
#define WIDX(d, k) W[(((d) * 3 + (k)) * 128 + kin) * 64 + o]
        float val;
        if (blk == 0)      val = WIDX(0, 0) + WIDX(1, 0) - WIDX(0, 2) - WIDX(1, 2);
        else if (blk == 1) val = WIDX(0, 1);
        else if (blk == 2) val = WIDX(1, 1);
        else if (blk == 3) val = 2.f * WIDX(0, 2);
        else               val = 2.f * WIDX(1, 2);
#undef WIDX
        Wt[t] = (f16)val;
    }
}

// ---------------------------------------------------------------------------
// node-major f16 propagation, merged CSR pair, XCD-chunked swizzle.
// x layout [v][NBAT][D] (= rr-major). One wave per node (D=128) or per 2
// nodes (D=64). Edge indices/weights: lane-parallel prefetch + shfl
// broadcast -> one load per wave per edge; gathers are fully contiguous
// NBAT*D*2-byte blocks (1KB for D=128).
template <int D, int HALFB>
__global__ __launch_bounds__(256) void k_prop16n(
        const int* __restrict__ pA, const int* __restrict__ sA, const float* __restrict__ wA,
        const f16* __restrict__ xA, f16* __restrict__ yA,
        const int* __restrict__ pB, const int* __restrict__ sB, const float* __restrict__ wB,
        const f16* __restrict__ xB, f16* __restrict__ yB) {
    constexpr int ROWE = NBAT * D;            // f16 elems per node block
    bool second = blockIdx.x >= HALFB;
    int local = second ? blockIdx.x - HALFB : blockIdx.x;
    int swz = (local & 7) * (HALFB / 8) + (local >> 3);   // bijective on [0,HALFB)
    const int* ptr   = second ? pB : pA;
    const int* srcs  = second ? sB : sA;
    const float* wts = second ? wB : wA;
    const f16* x     = second ? xB : xA;
    f16* y           = second ? yB : yA;
    int wid  = swz * 4 + (threadIdx.x >> 6);
    int lane = threadIdx.x & 63;

    int v, sub, chunk, shbase;
    if (D == 128) {            // 64 lanes cover one 1024B node block
        v = wid; sub = lane; chunk = 64; shbase = 0;
    } else {                   // 32-lane halves, 2 nodes per wave
        v = wid * 2 + (lane >> 5); sub = lane & 31; chunk = 32; shbase = lane & 32;
    }
    if (v >= NN) return;
    int j0 = ptr[v], j1 = ptr[v + 1];
    const f16* src = x + sub * 8;
    float acc[8] = {};
    for (int jc = j0; jc < j1; jc += chunk) {
        int n = j1 - jc; if (n > chunk) n = chunk;
        int lj = jc + sub;
        int   s_l = (lj < j1) ? srcs[lj] : 0;
        float w_l = (lj < j1) ? wts[lj] : 0.f;
        int q = 0;
        for (; q + 4 <= n; q += 4) {
            int s0 = __shfl(s_l, shbase | q);
            int s1 = __shfl(s_l, shbase | (q + 1));
            int s2 = __shfl(s_l, shbase | (q + 2));
            int s3 = __shfl(s_l, shbase | (q + 3));
            float w0 = __shfl(w_l, shbase | q);
            float w1 = __shfl(w_l, shbase | (q + 1));
            float w2 = __shfl(w_l, shbase | (q + 2));
            float w3 = __shfl(w_l, shbase | (q + 3));
            f16x8 g0 = *(const f16x8*)(src + (size_t)s0 * ROWE);
            f16x8 g1 = *(const f16x8*)(src + (size_t)s1 * ROWE);
            f16x8 g2 = *(const f16x8*)(src + (size_t)s2 * ROWE);
            f16x8 g3 = *(const f16x8*)(src + (size_t)s3 * ROWE);
#pragma unroll
            for (int e = 0; e < 8; e++)
                acc[e] += w0 * (float)g0[e] + w1 * (float)g1[e]
                        + w2 * (float)g2[e] + w3 * (float)g3[e];
        }
        for (; q < n; q++) {
            int s = __shfl(s_l, shbase | q);
            float w = __shfl(w_l, shbase | q);
            f16x8 g = *(const f16x8*)(src + (size_t)s * ROWE);
#pragma unroll
            for (int e = 0; e < 8; e++) acc[e] += w * (float)g[e];
        }
    }
    f16x8 o;
#pragma unroll
    for (int e = 0; e < 8; e++) o[e] = (f16)acc[e];
    *(f16x8*)(y + (size_t)v * ROWE + sub * 8) = o;
}

// ---------------------------------------------------------------------------
// MFMA gate matmuls: [40000,640]@[640,64], A assembled from 10 f16 chunk
// sources, all rr-major (rr = v*4+b). H/Z-out/final-out use original [b][v].
struct SrcTab16 {
    const f16* p[10];
    int ld[10];
    int co[10];
};

__device__ __forceinline__ float sigmf(float x) { return 1.f / (1.f + __expf(-x)); }
__device__ __forceinline__ float tanhfast(float x) {
    float e = __expf(2.f * x);
    return 1.f - 2.f / (e + 1.f);
}

// 64 rows x 64 cols per block, 4 waves; double-buffered LDS, 1 barrier/chunk.
__global__ __launch_bounds__(256) void k_gate_zr16(SrcTab16 tab,
        const f16* __restrict__ wtz, const f16* __restrict__ wtr,
        const float* __restrict__ bz, const float* __restrict__ br,
        const float* __restrict__ H, float* __restrict__ Z, f16* __restrict__ HR) {
    __shared__ f16 As[2][64 * 64];
    __shared__ f16 Ws[2][2][64 * 64];
    int tid = threadIdx.x;
    int l = tid & 63, w = tid >> 6;
    int g = l >> 4, li = l & 15;
    int rloc = w * 16 + li;
    int rb0 = blockIdx.x * 64;
    f32x4 accZ[4] = {}, accR[4] = {};
    f16x8 rA[2], rW[4];

    auto loadc = [&](int ch) {
        const f16* sp = tab.p[ch];
        int ld = tab.ld[ch], co = tab.co[ch];
#pragma unroll
        for (int i = 0; i < 2; i++) {
            int idx = i * 256 + tid;          // [0,512)
            int row = idx >> 3, slot = idx & 7;
            rA[i] = *(const f16x8*)(sp + (size_t)(rb0 + row) * ld + co + slot * 8);
        }
#pragma unroll
        for (int i = 0; i < 4; i++) {
            int idx = i * 256 + tid;          // [0,1024)
            int wsel = idx >> 9, id2 = idx & 511;
            int row = id2 >> 3, slot = id2 & 7;
            rW[i] = *(const f16x8*)((wsel ? wtr : wtz) + (size_t)row * 640 + ch * 64 + slot * 8);
        }
    };
    auto storec = [&](int buf) {
#pragma unroll
        for (int i = 0; i < 2; i++) {
            int idx = i * 256 + tid;
            int row = idx >> 3, slot = idx & 7;
            int byte = row * 128 + ((slot * 16) ^ ((row & 7) << 4));
            *(f16x8*)((char*)As[buf] + byte) = rA[i];
        }
#pragma unroll
        for (int i = 0; i < 4; i++) {
            int idx = i * 256 + tid;
            int wsel = idx >> 9, id2 = idx & 511;
            int row = id2 >> 3, slot = id2 & 7;
            int byte = row * 128 + ((slot * 16) ^ ((row & 7) << 4));
            *(f16x8*)((char*)Ws[buf][wsel] + byte) = rW[i];
        }
    };

    loadc(0); storec(0); __syncthreads();
    int cur = 0;
    for (int ch = 0; ch < 10; ch++) {
        if (ch + 1 < 10) loadc(ch + 1);
#pragma unroll
        for (int kk2 = 0; kk2 < 2; kk2++) {
            int k = kk2 * 32 + g * 8;
            f16x8 af = *(const f16x8*)((char*)As[cur] + rloc * 128 + ((k * 2) ^ ((rloc & 7) << 4)));
#pragma unroll
            for (int ct = 0; ct < 4; ct++) {
                int c = ct * 16 + li;
                int wbyte = c * 128 + ((k * 2) ^ ((c & 7) << 4));
                f16x8 bzf = *(const f16x8*)((char*)Ws[cur][0] + wbyte);
                f16x8 brf = *(const f16x8*)((char*)Ws[cur][1] + wbyte);
                accZ[ct] = __builtin_amdgcn_mfma_f32_16x16x32_f16(af, bzf, accZ[ct], 0, 0, 0);
                accR[ct] = __builtin_amdgcn_mfma_f32_16x16x32_f16(af, brf, accR[ct], 0, 0, 0);
            }
        }
        if (ch + 1 < 10) {
            storec(cur ^ 1);
            __syncthreads();
            cur ^= 1;
        }
    }
    // epilogue: C row(rr) = rb0 + w*16 + g*4 + q, col = ct*16 + li
#pragma unroll
    for (int ct = 0; ct < 4; ct++) {
        int c = ct * 16 + li;
        float zb = bz[c], rbv = br[c];
#pragma unroll
        for (int q = 0; q < 4; q++) {
            int rr = rb0 + w * 16 + g * 4 + q;
            int v = rr >> 2, b = rr & 3;
            size_t ho = ((size_t)b * NN + v) * 64 + c;
            float z = sigmf(accZ[ct][q] + zb);
            float r = sigmf(accR[ct][q] + rbv);
            Z[(size_t)rr * 64 + c] = z;
            HR[(size_t)rr * 64 + c] = (f16)(H[ho] * r);
        }
    }
}

__global__ __launch_bounds__(256) void k_gate_h16(SrcTab16 tab,
        const f16* __restrict__ wth, const float* __restrict__ bh,
        const float* __restrict__ H, const float* __restrict__ Z,
        float* __restrict__ out) {
    __shared__ f16 As[2][64 * 64];
    __shared__ f16 Ws[2][64 * 64];
    int tid = threadIdx.x;
    int l = tid & 63, w = tid >> 6;
    int g = l >> 4, li = l & 15;
    int rloc = w * 16 + li;
    int rb0 = blockIdx.x * 64;
    f32x4 acc[4] = {};
    f16x8 rA[2], rW[2];

    auto loadc = [&](int ch) {
        const f16* sp = tab.p[ch];
        int ld = tab.ld[ch], co = tab.co[ch];
#pragma unroll
        for (int i = 0; i < 2; i++) {
            int idx = i * 256 + tid;
            int row = idx >> 3, slot = idx & 7;
            rA[i] = *(const f16x8*)(sp + (size_t)(rb0 + row) * ld + co + slot * 8);
            rW[i] = *(const f16x8*)(wth + (size_t)row * 640 + ch * 64 + slot * 8);
        }
    };
    auto storec = [&](int buf) {
#pragma unroll
        for (int i = 0; i < 2; i++) {
            int idx = i * 256 + tid;
            int row = idx >> 3, slot = idx & 7;
            int byte = row * 128 + ((slot * 16) ^ ((row & 7) << 4));
            *(f16x8*)((char*)As[buf] + byte) = rA[i];
            *(f16x8*)((char*)Ws[buf] + byte) = rW[i];
        }
    };

    loadc(0); storec(0); __syncthreads();
    int cur = 0;
    for (int ch = 0; ch < 10; ch++) {
        if (ch + 1 < 10) loadc(ch + 1);
#pragma unroll
        for (int kk2 = 0; kk2 < 2; kk2++) {
            int k = kk2 * 32 + g * 8;
            f16x8 af = *(const f16x8*)((char*)As[cur] + rloc * 128 + ((k * 2) ^ ((rloc & 7) << 4)));
#pragma unroll
            for (int ct = 0; ct < 4; ct++) {
                int c = ct * 16 + li;
                int wbyte = c * 128 + ((k * 2) ^ ((c & 7) << 4));
                f16x8 bf = *(const f16x8*)((char*)Ws[cur] + wbyte);
                acc[ct] = __builtin_amdgcn_mfma_f32_16x16x32_f16(af, bf, acc[ct], 0, 0, 0);
            }
        }
        if (ch + 1 < 10) {
            storec(cur ^ 1);
            __syncthreads();
            cur ^= 1;
        }
    }
#pragma unroll
    for (int ct = 0; ct < 4; ct++) {
        int c = ct * 16 + li;
        float hb = bh[c];
#pragma unroll
        for (int q = 0; q < 4; q++) {
            int rr = rb0 + w * 16 + g * 4 + q;
            int v = rr >> 2, b = rr & 3;
            size_t ho = ((size_t)b * NN + v) * 64 + c;
            float ht = tanhfast(acc[ct][q] + hb);
            float z = Z[(size_t)rr * 64 + c];
            out[ho] = z * H[ho] + (1.f - z) * ht;
        }
    }
}

// ---------------------------------------------------------------------------
extern "C" void kernel_launch(void* const* d_in, const int* in_sizes, int n_in,
                              void* d_out, int out_size, void* d_ws, size_t ws_size,
                              hipStream_t stream) {
    const float* X  = (const float*)d_in[0];
    const float* H  = (const float*)d_in[1];
    const float* ew = (const float*)d_in[2];
    const float* Wz = (const float*)d_in[3];
    const float* bz = (const float*)d_in[4];
    const float* Wr = (const float*)d_in[5];
    const float* br = (const float*)d_in[6];
    const float* Wh = (const float*)d_in[7];
    const float* bh = (const float*)d_in[8];
    const int*   ei = (const int*)d_in[9];
    const int* row = ei;
    const int* col = ei + NE;
    float* out = (float*)d_out;

    char* ws = (char*)d_ws;
    size_t off = 0;
    auto alloc = [&](size_t bytes) -> void* {
        void* p = ws + off;
        off += (bytes + 255) & ~(size_t)255;
        return p;
    };
    float* degs     = (float*)alloc(2 * NN * 4);
    int*   cnts     = (int*)alloc(2 * NN * 4);
    size_t zero_span = off;                      // degs..cnts: one memset
    int*   ptr_out  = (int*)alloc((NN + 1) * 4);
    int*   cur_out  = (int*)alloc(NN * 4);
    int*   srcs_out = (int*)alloc(NE * 4);
    float* w_out    = (float*)alloc(NE * 4);
    int*   ptr_in   = (int*)alloc((NN + 1) * 4);
    int*   cur_in   = (int*)alloc(NN * 4);
    int*   srcs_in  = (int*)alloc(NE * 4);
    float* w_in     = (float*)alloc(NE * 4);
    const size_t nBN = (size_t)NBAT * NN;
    f16* Xh16 = (f16*)alloc(nBN * 128 * 2);
    f16* P1o  = (f16*)alloc(nBN * 128 * 2);
    f16* P1i  = (f16*)alloc(nBN * 128 * 2);
    f16* S1o  = (f16*)alloc(nBN * 128 * 2);
    f16* S1i  = (f16*)alloc(nBN * 128 * 2);
    f16* HRb  = (f16*)alloc(nBN * 64 * 2);
    f16* T1o  = (f16*)alloc(nBN * 64 * 2);
    f16* T1i  = (f16*)alloc(nBN * 64 * 2);
    f16* T2o  = (f16*)alloc(nBN * 64 * 2);
    f16* T2i  = (f16*)alloc(nBN * 64 * 2);
    float* Zb = (float*)alloc(nBN * 64 * 4);
    f16* Wt   = (f16*)alloc(3 * 64 * 640 * 2);
    f16* wtz = Wt;
    f16* wtr = Wt + 64 * 640;
    f16* wth = Wt + 2 * 64 * 640;

    float* deg_out = degs;
    float* deg_in  = degs + NN;
    int* cnt_out = cnts;
    int* cnt_in  = cnts + NN;

    hipMemsetAsync(degs, 0, zero_span, stream);

    int gE = (NE + 255) / 256;
    k_degcnt<<<gE, 256, 0, stream>>>(ew, row, col, deg_out, deg_in, cnt_out, cnt_in);
    k_scan<<<2, 1024, 0, stream>>>(cnt_out, ptr_out, cur_out, cnt_in, ptr_in, cur_in);
    k_fill<<<gE, 256, 0, stream>>>(row, col, deg_out, deg_in,
                                   cur_out, srcs_out, w_out, cur_in, srcs_in, w_in);

    // node-major f16 concat + transposed weights (one launch)
    k_prep<<<XHB + WPB, 256, 0, stream>>>(X, H, Xh16, Wz, Wr, Wh, Wt);

    // half-grids: one wave/node (D=128) or 2 nodes/wave (D=64), 4 waves/block
    constexpr int HB128 = ((NN + 3) / 4 + 7) & ~7;        // 2504 blocks
    constexpr int HB64  = ((NN / 2 + 3) / 4 + 7) & ~7;    // 1256 blocks

    // P1o = A_out [X|H], P1i = A_in [X|H]
    k_prop16n<128, HB128><<<2 * HB128, 256, 0, stream>>>(
        ptr_out, srcs_out, w_out, Xh16, P1o, ptr_in, srcs_in, w_in, Xh16, P1i);
    // S1o = A_out P1o, S1i = A_in P1i
    k_prop16n<128, HB128><<<2 * HB128, 256, 0, stream>>>(
        ptr_out, srcs_out, w_out, P1o, S1o, ptr_in, srcs_in, w_in, P1i, S1i);

    SrcTab16 zr;
    {
        const f16* ps[10] = {Xh16, Xh16, P1o, P1o, P1i, P1i, S1o, S1o, S1i, S1i};
        int lds[10] = {128, 128, 128, 128, 128, 128, 128, 128, 128, 128};
        int cos_[10] = {0, 64, 0, 64, 0, 64, 0, 64, 0, 64};
        for (int i = 0; i < 10; i++) { zr.p[i] = ps[i]; zr.ld[i] = lds[i]; zr.co[i] = cos_[i]; }
    }
    int gMM = (int)(nBN / 64);
    k_gate_zr16<<<gMM, 256, 0, stream>>>(zr, wtz, wtr, bz, br, H, Zb, HRb);

    // props of HR (64-dim)
    k_prop16n<64, HB64><<<2 * HB64, 256, 0, stream>>>(
        ptr_out, srcs_out, w_out, HRb, T1o, ptr_in, srcs_in, w_in, HRb, T1i);
    k_prop16n<64, HB64><<<2 * HB64, 256, 0, stream>>>(
        ptr_out, srcs_out, w_out, T1o, T2o, ptr_in, srcs_in, w_in, T1i, T2i);

    SrcTab16 hh;
    {
        const f16* ps[10] = {Xh16, HRb, P1o, T1o, P1i, T1i, S1o, T2o, S1i, T2i};
        int lds[10] = {128, 64, 128, 64, 128, 64, 128, 64, 128, 64};
        int cos_[10] = {0, 0, 0, 0, 0, 0, 0, 0, 0, 0};
        for (int i = 0; i < 10; i++) { hh.p[i] = ps[i]; hh.ld[i] = lds[i]; hh.co[i] = cos_[i]; }
    }
    k_gate_h16<<<gMM, 256, 0, stream>>>(hh, wth, bh, H, Zb, out);
}